// Round 2
// baseline (1145.809 us; speedup 1.0000x reference)
//
#include <hip/hip_runtime.h>
#include <hip/hip_bf16.h>

// Problem constants (from reference)
#define NTOK 8192      // B*T = 4*2048
#define DIM 1024
#define NEXP 8
#define HID 2816
#define NPAIR (NTOK * 2)   // TOP_K = 2

// GEMM tiling (m97 structure: 128x128 tile, BK=64, 4 waves of 4x4 16x16 frags)
#define BM 128
#define BN 128
#define BK 64

typedef unsigned short u16;
typedef __attribute__((ext_vector_type(8))) short short8;   // 8 x bf16 fragment
typedef __attribute__((ext_vector_type(4))) float f32x4;    // MFMA accumulator

static __device__ __forceinline__ u16 f2bf(float f) {
  union { float f; unsigned u; } v; v.f = f;
  unsigned r = v.u + 0x7fff + ((v.u >> 16) & 1);  // RTNE
  return (u16)(r >> 16);
}

// async global->LDS, 16B per lane; LDS dest must be wave-uniform base
static __device__ __forceinline__ void gload16(const void* g, void* l) {
  __builtin_amdgcn_global_load_lds(
      (const __attribute__((address_space(1))) unsigned*)(g),
      (__attribute__((address_space(3))) unsigned*)(l), 16, 0, 0);
}

// ---------------- fp32 -> bf16 conversion (vectorized, grid-stride) ----------
__global__ void cvt_kernel(const float* __restrict__ src, u16* __restrict__ dst, int n) {
  int stride = gridDim.x * blockDim.x;
  for (int i = blockIdx.x * blockDim.x + threadIdx.x; i * 4 < n; i += stride) {
    float4 v = *reinterpret_cast<const float4*>(src + (size_t)i * 4);
    ushort4 o;
    o.x = f2bf(v.x); o.y = f2bf(v.y); o.z = f2bf(v.z); o.w = f2bf(v.w);
    *reinterpret_cast<ushort4*>(dst + (size_t)i * 4) = o;
  }
}

// ---------------- router: logits -> softmax -> top2 -> renorm ----------------
__global__ void router_kernel(const float* __restrict__ x, const float* __restrict__ gw,
                              int* __restrict__ cnt, int* __restrict__ tok_e,
                              float* __restrict__ tok_w) {
  int t = blockIdx.x;
  int lane = threadIdx.x;  // 64 threads = 1 wave
  const float* xr = x + (size_t)t * DIM;
  float acc[NEXP];
#pragma unroll
  for (int e = 0; e < NEXP; ++e) acc[e] = 0.f;
  for (int d = lane; d < DIM; d += 64) {
    float xv = xr[d];
#pragma unroll
    for (int e = 0; e < NEXP; ++e) acc[e] += xv * gw[e * DIM + d];
  }
#pragma unroll
  for (int e = 0; e < NEXP; ++e) {
#pragma unroll
    for (int o = 32; o > 0; o >>= 1) acc[e] += __shfl_xor(acc[e], o);
  }
  if (lane == 0) {
    float m = acc[0];
#pragma unroll
    for (int e = 1; e < NEXP; ++e) m = fmaxf(m, acc[e]);
    float p[NEXP];
#pragma unroll
    for (int e = 0; e < NEXP; ++e) p[e] = __expf(acc[e] - m);
    int e0 = 0; float b0 = p[0];
#pragma unroll
    for (int e = 1; e < NEXP; ++e) if (p[e] > b0) { e0 = e; b0 = p[e]; }
    int e1 = -1; float b1 = -1.f;
#pragma unroll
    for (int e = 0; e < NEXP; ++e) if (e != e0 && p[e] > b1) { e1 = e; b1 = p[e]; }
    float inv = 1.f / (b0 + b1);   // softmax denom cancels in the renorm ratio
    atomicAdd(&cnt[e0], 1);
    atomicAdd(&cnt[e1], 1);
    tok_e[2 * t] = e0; tok_e[2 * t + 1] = e1;
    tok_w[2 * t] = b0 * inv; tok_w[2 * t + 1] = b1 * inv;
  }
}

// ---------------- tiny prefix over 8 experts -------------------------------
__global__ void prefix_kernel(const int* __restrict__ cnt, int* __restrict__ off,
                              int* __restrict__ fill) {
  if (threadIdx.x == 0 && blockIdx.x == 0) {
    int s = 0;
    for (int e = 0; e < NEXP; ++e) { off[e] = s; s += cnt[e]; fill[e] = 0; }
    off[NEXP] = s;   // == NPAIR
  }
}

// ---------------- scatter tokens into per-expert slot lists ----------------
__global__ void scatter_kernel(const int* __restrict__ tok_e, const float* __restrict__ tok_w,
                               const int* __restrict__ off, int* __restrict__ fill,
                               int* __restrict__ pair_tok, float* __restrict__ pair_w) {
  int t = blockIdx.x * blockDim.x + threadIdx.x;
  if (t >= NTOK) return;
#pragma unroll
  for (int k = 0; k < 2; ++k) {
    int e = tok_e[2 * t + k];
    int slot = off[e] + atomicAdd(&fill[e], 1);
    pair_tok[slot] = t;
    pair_w[slot] = tok_w[2 * t + k];
  }
}

// ---------------- GEMM1: h = silu(x @ w1^T) * (x @ w3^T) -------------------
// grid: (NPAIR/BM, HID/BN, NEXP); block 256 = 4 waves (2x2), each 64x64 out
__launch_bounds__(256, 2)
__global__ void gemm1_kernel(const u16* __restrict__ xb, const u16* __restrict__ w1b,
                             const u16* __restrict__ w3b, u16* __restrict__ hbuf,
                             const int* __restrict__ off, const int* __restrict__ pair_tok) {
  int e = blockIdx.z;
  int mbase = off[e] + blockIdx.x * BM;
  int mend = off[e + 1];
  if (mbase >= mend) return;
  int nrows = mend - mbase; if (nrows > BM) nrows = BM;
  int n0 = blockIdx.y * BN;

  __shared__ u16 As[BM * BK];    // linear [row][64], row-major
  __shared__ u16 B1s[BN * BK];
  __shared__ u16 B3s[BN * BK];

  int tid = threadIdx.x;
  int lane = tid & 63;
  int wid = tid >> 6;
  int wr = wid >> 1, wc = wid & 1;          // 2x2 wave grid, 64x64 each
  int lrow = lane & 15, kgrp = lane >> 4;

  // staging geometry: issue i covers rows i*32 + wid*8 + lane/8, col (lane%8)*8
  int scol = (lane & 7) * 8;
  const u16* pA[4]; const u16* pB1[4]; const u16* pB3[4];
  const u16* w1base = w1b + (size_t)e * HID * DIM;
  const u16* w3base = w3b + (size_t)e * HID * DIM;
#pragma unroll
  for (int i = 0; i < 4; ++i) {
    int r = i * 32 + wid * 8 + (lane >> 3);
    int ra = r < nrows ? r : nrows - 1;         // clamp ragged tile
    int tok = pair_tok[mbase + ra];
    pA[i]  = xb + (size_t)tok * DIM + scol;
    pB1[i] = w1base + (size_t)(n0 + r) * DIM + scol;
    pB3[i] = w3base + (size_t)(n0 + r) * DIM + scol;
  }

  f32x4 acc1[4][4], acc3[4][4];
#pragma unroll
  for (int i = 0; i < 4; ++i)
#pragma unroll
    for (int j = 0; j < 4; ++j) { acc1[i][j] = (f32x4)0.f; acc3[i][j] = (f32x4)0.f; }

  for (int kk = 0; kk < DIM; kk += BK) {
    __syncthreads();   // prior iter's reads done before overwrite
#pragma unroll
    for (int i = 0; i < 4; ++i) {
      int lofs = i * 2048 + wid * 512;   // u16 units; 16B/lane added by HW
      gload16(pA[i] + kk,  &As[lofs]);
      gload16(pB1[i] + kk, &B1s[lofs]);
      gload16(pB3[i] + kk, &B3s[lofs]);
    }
    __syncthreads();   // drains vmcnt -> LDS tile ready
#pragma unroll
    for (int ks = 0; ks < 2; ++ks) {
      int kc = ks * 32 + kgrp * 8;
      short8 a[4], b1[4], b3[4];
#pragma unroll
      for (int m = 0; m < 4; ++m)
        a[m] = *(const short8*)&As[(wr * 64 + m * 16 + lrow) * BK + kc];
#pragma unroll
      for (int n = 0; n < 4; ++n) {
        b1[n] = *(const short8*)&B1s[(wc * 64 + n * 16 + lrow) * BK + kc];
        b3[n] = *(const short8*)&B3s[(wc * 64 + n * 16 + lrow) * BK + kc];
      }
#pragma unroll
      for (int m = 0; m < 4; ++m)
#pragma unroll
        for (int n = 0; n < 4; ++n) {
          acc1[m][n] = __builtin_amdgcn_mfma_f32_16x16x32_bf16(a[m], b1[n], acc1[m][n], 0, 0, 0);
          acc3[m][n] = __builtin_amdgcn_mfma_f32_16x16x32_bf16(a[m], b3[n], acc3[m][n], 0, 0, 0);
        }
    }
  }
  // epilogue: silu(acc1)*acc3 -> bf16 h
#pragma unroll
  for (int m = 0; m < 4; ++m)
#pragma unroll
    for (int n = 0; n < 4; ++n)
#pragma unroll
      for (int r = 0; r < 4; ++r) {
        int rowt = wr * 64 + m * 16 + kgrp * 4 + r;   // C/D: row=(lane>>4)*4+r, col=lane&15
        if (rowt < nrows) {
          float v1 = acc1[m][n][r], v3 = acc3[m][n][r];
          float hv = v1 / (1.f + __expf(-v1)) * v3;
          hbuf[(size_t)(mbase + rowt) * HID + (n0 + wc * 64 + n * 16 + lrow)] = f2bf(hv);
        }
      }
}

// ---------------- GEMM2: out[token] += (h @ w2^T) * pair_w -----------------
// grid: (NPAIR/BM, DIM/BN, NEXP); block 256
__launch_bounds__(256, 2)
__global__ void gemm2_kernel(const u16* __restrict__ hbuf, const u16* __restrict__ w2b,
                             float* __restrict__ out, const int* __restrict__ off,
                             const int* __restrict__ pair_tok, const float* __restrict__ pair_w) {
  int e = blockIdx.z;
  int mbase = off[e] + blockIdx.x * BM;
  int mend = off[e + 1];
  if (mbase >= mend) return;
  int nrows = mend - mbase; if (nrows > BM) nrows = BM;
  int n0 = blockIdx.y * BN;

  __shared__ u16 As[BM * BK];
  __shared__ u16 Bs[BN * BK];

  int tid = threadIdx.x;
  int lane = tid & 63;
  int wid = tid >> 6;
  int wr = wid >> 1, wc = wid & 1;
  int lrow = lane & 15, kgrp = lane >> 4;

  int scol = (lane & 7) * 8;
  const u16* pA[4]; const u16* pB[4];
  const u16* w2base = w2b + (size_t)e * DIM * HID;
#pragma unroll
  for (int i = 0; i < 4; ++i) {
    int r = i * 32 + wid * 8 + (lane >> 3);
    int ra = r < nrows ? r : nrows - 1;
    pA[i] = hbuf + (size_t)(mbase + ra) * HID + scol;
    pB[i] = w2base + (size_t)(n0 + r) * HID + scol;
  }

  f32x4 acc[4][4];
#pragma unroll
  for (int i = 0; i < 4; ++i)
#pragma unroll
    for (int j = 0; j < 4; ++j) acc[i][j] = (f32x4)0.f;

  for (int kk = 0; kk < HID; kk += BK) {
    __syncthreads();
#pragma unroll
    for (int i = 0; i < 4; ++i) {
      int lofs = i * 2048 + wid * 512;
      gload16(pA[i] + kk, &As[lofs]);
      gload16(pB[i] + kk, &Bs[lofs]);
    }
    __syncthreads();
#pragma unroll
    for (int ks = 0; ks < 2; ++ks) {
      int kc = ks * 32 + kgrp * 8;
      short8 a[4], b[4];
#pragma unroll
      for (int m = 0; m < 4; ++m)
        a[m] = *(const short8*)&As[(wr * 64 + m * 16 + lrow) * BK + kc];
#pragma unroll
      for (int n = 0; n < 4; ++n)
        b[n] = *(const short8*)&Bs[(wc * 64 + n * 16 + lrow) * BK + kc];
#pragma unroll
      for (int m = 0; m < 4; ++m)
#pragma unroll
        for (int n = 0; n < 4; ++n)
          acc[m][n] = __builtin_amdgcn_mfma_f32_16x16x32_bf16(a[m], b[n], acc[m][n], 0, 0, 0);
    }
  }
#pragma unroll
  for (int m = 0; m < 4; ++m)
#pragma unroll
    for (int n = 0; n < 4; ++n)
#pragma unroll
      for (int r = 0; r < 4; ++r) {
        int rowt = wr * 64 + m * 16 + kgrp * 4 + r;
        if (rowt < nrows) {
          int slot = mbase + rowt;
          int tok = pair_tok[slot];
          float w = pair_w[slot];
          atomicAdd(&out[(size_t)tok * DIM + (n0 + wc * 64 + n * 16 + lrow)],
                    acc[m][n][r] * w);
        }
      }
}

extern "C" void kernel_launch(void* const* d_in, const int* in_sizes, int n_in,
                              void* d_out, int out_size, void* d_ws, size_t ws_size,
                              hipStream_t stream) {
  const float* x  = (const float*)d_in[0];
  const float* gw = (const float*)d_in[1];
  const float* w1 = (const float*)d_in[2];
  const float* w3 = (const float*)d_in[3];
  const float* w2 = (const float*)d_in[4];
  float* out = (float*)d_out;

  // workspace layout (~248 MB)
  char* base = (char*)d_ws;
  size_t o = 0;
  auto alloc = [&](size_t bytes) {
    void* r = base + o;
    o = (o + bytes + 255) & ~(size_t)255;
    return r;
  };
  u16* xb      = (u16*)alloc((size_t)NTOK * DIM * 2);
  u16* w1b     = (u16*)alloc((size_t)NEXP * HID * DIM * 2);
  u16* w3b     = (u16*)alloc((size_t)NEXP * HID * DIM * 2);
  u16* w2b     = (u16*)alloc((size_t)NEXP * DIM * HID * 2);
  u16* hbuf    = (u16*)alloc((size_t)NPAIR * HID * 2);
  int* pair_tok = (int*)alloc((size_t)NPAIR * 4);
  float* pair_w = (float*)alloc((size_t)NPAIR * 4);
  int* tok_e    = (int*)alloc((size_t)NTOK * 2 * 4);
  float* tok_w  = (float*)alloc((size_t)NTOK * 2 * 4);
  int* cnt      = (int*)alloc(NEXP * 4);
  int* eoff     = (int*)alloc((NEXP + 1) * 4);
  int* fill     = (int*)alloc(NEXP * 4);

  hipMemsetAsync(d_out, 0, (size_t)out_size * sizeof(float), stream);
  hipMemsetAsync(cnt, 0, NEXP * sizeof(int), stream);

  cvt_kernel<<<2048, 256, 0, stream>>>(x,  xb,  NTOK * DIM);
  cvt_kernel<<<2048, 256, 0, stream>>>(w1, w1b, NEXP * HID * DIM);
  cvt_kernel<<<2048, 256, 0, stream>>>(w3, w3b, NEXP * HID * DIM);
  cvt_kernel<<<2048, 256, 0, stream>>>(w2, w2b, NEXP * DIM * HID);

  router_kernel<<<NTOK, 64, 0, stream>>>(x, gw, cnt, tok_e, tok_w);
  prefix_kernel<<<1, 64, 0, stream>>>(cnt, eoff, fill);
  scatter_kernel<<<NTOK / 256, 256, 0, stream>>>(tok_e, tok_w, eoff, fill, pair_tok, pair_w);

  gemm1_kernel<<<dim3(NPAIR / BM, HID / BN, NEXP), 256, 0, stream>>>(
      xb, w1b, w3b, hbuf, eoff, pair_tok);
  gemm2_kernel<<<dim3(NPAIR / BM, DIM / BN, NEXP), 256, 0, stream>>>(
      hbuf, w2b, out, eoff, pair_tok, pair_w);
}

// Round 3
// 1020.719 us; speedup vs baseline: 1.1226x; 1.1226x over previous
//
#include <hip/hip_runtime.h>
#include <hip/hip_bf16.h>

// Problem constants (from reference)
#define NTOK 8192      // B*T = 4*2048
#define DIM 1024
#define NEXP 8
#define HID 2816
#define NPAIR (NTOK * 2)   // TOP_K = 2

#define BK 64
#define G1_BM 128
#define G1_BN 64    // h-columns per block (w1 and w3 rows staged separately)
#define G2_BM 128
#define G2_BN 128

typedef unsigned short u16;
typedef __attribute__((ext_vector_type(8))) short short8;   // 8 x bf16 fragment
typedef __attribute__((ext_vector_type(4))) float f32x4;    // MFMA accumulator

static __device__ __forceinline__ u16 f2bf(float f) {
  union { float f; unsigned u; } v; v.f = f;
  unsigned r = v.u + 0x7fff + ((v.u >> 16) & 1);  // RTNE
  return (u16)(r >> 16);
}

// async global->LDS, 16B per lane; LDS dest is wave-uniform base + lane*16B
static __device__ __forceinline__ void gload16(const void* g, void* l) {
  __builtin_amdgcn_global_load_lds(
      (const __attribute__((address_space(1))) unsigned*)(g),
      (__attribute__((address_space(3))) unsigned*)(l), 16, 0, 0);
}

// ---------------- fp32 -> bf16 conversion (vectorized, grid-stride) ----------
__global__ void cvt_kernel(const float* __restrict__ src, u16* __restrict__ dst, int n) {
  int stride = gridDim.x * blockDim.x;
  for (int i = blockIdx.x * blockDim.x + threadIdx.x; i * 4 < n; i += stride) {
    float4 v = *reinterpret_cast<const float4*>(src + (size_t)i * 4);
    ushort4 o;
    o.x = f2bf(v.x); o.y = f2bf(v.y); o.z = f2bf(v.z); o.w = f2bf(v.w);
    *reinterpret_cast<ushort4*>(dst + (size_t)i * 4) = o;
  }
}

// ---------------- router: logits -> softmax -> top2 -> renorm ----------------
__global__ void router_kernel(const float* __restrict__ x, const float* __restrict__ gw,
                              int* __restrict__ cnt, int* __restrict__ tok_e,
                              float* __restrict__ tok_w) {
  int t = blockIdx.x;
  int lane = threadIdx.x;  // 64 threads = 1 wave
  const float* xr = x + (size_t)t * DIM;
  float acc[NEXP];
#pragma unroll
  for (int e = 0; e < NEXP; ++e) acc[e] = 0.f;
  for (int d = lane; d < DIM; d += 64) {
    float xv = xr[d];
#pragma unroll
    for (int e = 0; e < NEXP; ++e) acc[e] += xv * gw[e * DIM + d];
  }
#pragma unroll
  for (int e = 0; e < NEXP; ++e) {
#pragma unroll
    for (int o = 32; o > 0; o >>= 1) acc[e] += __shfl_xor(acc[e], o);
  }
  if (lane == 0) {
    float m = acc[0];
#pragma unroll
    for (int e = 1; e < NEXP; ++e) m = fmaxf(m, acc[e]);
    float p[NEXP];
#pragma unroll
    for (int e = 0; e < NEXP; ++e) p[e] = __expf(acc[e] - m);
    int e0 = 0; float b0 = p[0];
#pragma unroll
    for (int e = 1; e < NEXP; ++e) if (p[e] > b0) { e0 = e; b0 = p[e]; }
    int e1 = -1; float b1 = -1.f;
#pragma unroll
    for (int e = 0; e < NEXP; ++e) if (e != e0 && p[e] > b1) { e1 = e; b1 = p[e]; }
    float inv = 1.f / (b0 + b1);   // softmax denom cancels in the renorm ratio
    atomicAdd(&cnt[e0], 1);
    atomicAdd(&cnt[e1], 1);
    tok_e[2 * t] = e0; tok_e[2 * t + 1] = e1;
    tok_w[2 * t] = b0 * inv; tok_w[2 * t + 1] = b1 * inv;
  }
}

// ---------------- tiny prefix over 8 experts -------------------------------
__global__ void prefix_kernel(const int* __restrict__ cnt, int* __restrict__ off,
                              int* __restrict__ fill) {
  if (threadIdx.x == 0 && blockIdx.x == 0) {
    int s = 0;
    for (int e = 0; e < NEXP; ++e) { off[e] = s; s += cnt[e]; fill[e] = 0; }
    off[NEXP] = s;   // == NPAIR
  }
}

// ---------------- scatter tokens into per-expert slot lists ----------------
__global__ void scatter_kernel(const int* __restrict__ tok_e, const float* __restrict__ tok_w,
                               const int* __restrict__ off, int* __restrict__ fill,
                               int* __restrict__ pair_tok, float* __restrict__ pair_w,
                               int* __restrict__ t2s) {
  int t = blockIdx.x * blockDim.x + threadIdx.x;
  if (t >= NTOK) return;
#pragma unroll
  for (int k = 0; k < 2; ++k) {
    int e = tok_e[2 * t + k];
    int slot = off[e] + atomicAdd(&fill[e], 1);
    pair_tok[slot] = t;
    pair_w[slot] = tok_w[2 * t + k];
    t2s[2 * t + k] = slot;
  }
}

// ---------------- GEMM1: h = silu(x @ w1^T) * (x @ w3^T) -------------------
// 128x64 tile (64 h-cols), 4 waves (2x2), each wave 64x32 per matmul.
// acc = 16 f32x4 = 64 acc regs (m97 profile). LDS 32KB.
__launch_bounds__(256, 2)
__global__ void gemm1_kernel(const u16* __restrict__ xb, const u16* __restrict__ w1b,
                             const u16* __restrict__ w3b, u16* __restrict__ hbuf,
                             const int* __restrict__ off, const int* __restrict__ pair_tok) {
  int e = blockIdx.z;
  int mbase = off[e] + blockIdx.x * G1_BM;
  int mend = off[e + 1];
  if (mbase >= mend) return;
  int nrows = mend - mbase; if (nrows > G1_BM) nrows = G1_BM;
  int n0 = blockIdx.y * G1_BN;

  __shared__ u16 As[G1_BM * BK];    // 16KB, linear [row][64]
  __shared__ u16 B1s[G1_BN * BK];   // 8KB
  __shared__ u16 B3s[G1_BN * BK];   // 8KB

  int tid = threadIdx.x;
  int lane = tid & 63;
  int wid = tid >> 6;
  int wr = wid >> 1, wc = wid & 1;          // 2(M) x 2(N) wave grid
  int lrow = lane & 15, kgrp = lane >> 4;

  // staging: issue i covers rows i*32 + tid/8, col (tid%8)*8 (8 u16 = 16B)
  int srow = tid >> 3;          // 0..31
  int scol = (tid & 7) * 8;
  const u16* pA[4]; const u16* pB1[2]; const u16* pB3[2];
  const u16* w1base = w1b + (size_t)e * HID * DIM;
  const u16* w3base = w3b + (size_t)e * HID * DIM;
#pragma unroll
  for (int i = 0; i < 4; ++i) {
    int r = i * 32 + srow;
    int ra = r < nrows ? r : nrows - 1;       // clamp ragged tile
    int tok = pair_tok[mbase + ra];
    pA[i] = xb + (size_t)tok * DIM + scol;
  }
#pragma unroll
  for (int i = 0; i < 2; ++i) {
    int r = i * 32 + srow;
    pB1[i] = w1base + (size_t)(n0 + r) * DIM + scol;
    pB3[i] = w3base + (size_t)(n0 + r) * DIM + scol;
  }

  f32x4 acc1[4][2], acc3[4][2];
#pragma unroll
  for (int m = 0; m < 4; ++m)
#pragma unroll
    for (int n = 0; n < 2; ++n) { acc1[m][n] = (f32x4)0.f; acc3[m][n] = (f32x4)0.f; }

  for (int kk = 0; kk < DIM; kk += BK) {
    __syncthreads();   // prior iter's reads done before overwrite
#pragma unroll
    for (int i = 0; i < 4; ++i)
      gload16(pA[i] + kk, &As[i * 2048 + wid * 512]);
#pragma unroll
    for (int i = 0; i < 2; ++i) {
      gload16(pB1[i] + kk, &B1s[i * 2048 + wid * 512]);
      gload16(pB3[i] + kk, &B3s[i * 2048 + wid * 512]);
    }
    __syncthreads();   // compiler drains vmcnt before barrier -> tile ready
#pragma unroll
    for (int ks = 0; ks < 2; ++ks) {
      int kc = ks * 32 + kgrp * 8;
      short8 a[4], b1[2], b3[2];
#pragma unroll
      for (int m = 0; m < 4; ++m)
        a[m] = *(const short8*)&As[(wr * 64 + m * 16 + lrow) * BK + kc];
#pragma unroll
      for (int n = 0; n < 2; ++n) {
        b1[n] = *(const short8*)&B1s[(wc * 32 + n * 16 + lrow) * BK + kc];
        b3[n] = *(const short8*)&B3s[(wc * 32 + n * 16 + lrow) * BK + kc];
      }
#pragma unroll
      for (int m = 0; m < 4; ++m)
#pragma unroll
        for (int n = 0; n < 2; ++n) {
          acc1[m][n] = __builtin_amdgcn_mfma_f32_16x16x32_bf16(a[m], b1[n], acc1[m][n], 0, 0, 0);
          acc3[m][n] = __builtin_amdgcn_mfma_f32_16x16x32_bf16(a[m], b3[n], acc3[m][n], 0, 0, 0);
        }
    }
  }
  // epilogue: silu(acc1)*acc3 -> bf16 h
#pragma unroll
  for (int m = 0; m < 4; ++m)
#pragma unroll
    for (int n = 0; n < 2; ++n)
#pragma unroll
      for (int r = 0; r < 4; ++r) {
        int rowt = wr * 64 + m * 16 + kgrp * 4 + r;   // C/D: row=(lane>>4)*4+r, col=lane&15
        if (rowt < nrows) {
          float v1 = acc1[m][n][r], v3 = acc3[m][n][r];
          float hv = v1 / (1.f + __expf(-v1)) * v3;
          hbuf[(size_t)(mbase + rowt) * HID + (n0 + wc * 32 + n * 16 + lrow)] = f2bf(hv);
        }
      }
}

// ---------------- GEMM2: y2[slot] = (h @ w2^T) * pair_w --------------------
// m97 structure: 128x128 tile, 4 waves each 64x64, acc 16 f32x4. No atomics.
__launch_bounds__(256, 2)
__global__ void gemm2_kernel(const u16* __restrict__ hbuf, const u16* __restrict__ w2b,
                             float* __restrict__ y2, const int* __restrict__ off,
                             const float* __restrict__ pair_w) {
  int e = blockIdx.z;
  int mbase = off[e] + blockIdx.x * G2_BM;
  int mend = off[e + 1];
  if (mbase >= mend) return;
  int nrows = mend - mbase; if (nrows > G2_BM) nrows = G2_BM;
  int n0 = blockIdx.y * G2_BN;

  __shared__ u16 As[G2_BM * BK];   // 16KB
  __shared__ u16 Bs[G2_BN * BK];   // 16KB

  int tid = threadIdx.x;
  int lane = tid & 63;
  int wid = tid >> 6;
  int wr = wid >> 1, wc = wid & 1;
  int lrow = lane & 15, kgrp = lane >> 4;

  int srow = tid >> 3;
  int scol = (tid & 7) * 8;
  const u16* pA[4]; const u16* pB[4];
  const u16* w2base = w2b + (size_t)e * DIM * HID;
#pragma unroll
  for (int i = 0; i < 4; ++i) {
    int r = i * 32 + srow;
    int ra = r < nrows ? r : nrows - 1;
    pA[i] = hbuf + (size_t)(mbase + ra) * HID + scol;
    pB[i] = w2base + (size_t)(n0 + r) * HID + scol;
  }

  f32x4 acc[4][4];
#pragma unroll
  for (int m = 0; m < 4; ++m)
#pragma unroll
    for (int n = 0; n < 4; ++n) acc[m][n] = (f32x4)0.f;

  for (int kk = 0; kk < HID; kk += BK) {
    __syncthreads();
#pragma unroll
    for (int i = 0; i < 4; ++i) {
      gload16(pA[i] + kk, &As[i * 2048 + wid * 512]);
      gload16(pB[i] + kk, &Bs[i * 2048 + wid * 512]);
    }
    __syncthreads();
#pragma unroll
    for (int ks = 0; ks < 2; ++ks) {
      int kc = ks * 32 + kgrp * 8;
      short8 a[4], b[4];
#pragma unroll
      for (int m = 0; m < 4; ++m)
        a[m] = *(const short8*)&As[(wr * 64 + m * 16 + lrow) * BK + kc];
#pragma unroll
      for (int n = 0; n < 4; ++n)
        b[n] = *(const short8*)&Bs[(wc * 64 + n * 16 + lrow) * BK + kc];
#pragma unroll
      for (int m = 0; m < 4; ++m)
#pragma unroll
        for (int n = 0; n < 4; ++n)
          acc[m][n] = __builtin_amdgcn_mfma_f32_16x16x32_bf16(a[m], b[n], acc[m][n], 0, 0, 0);
    }
  }
#pragma unroll
  for (int m = 0; m < 4; ++m) {
#pragma unroll
    for (int r = 0; r < 4; ++r) {
      int rowt = wr * 64 + m * 16 + kgrp * 4 + r;
      if (rowt < nrows) {
        int slot = mbase + rowt;
        float w = pair_w[slot];
#pragma unroll
        for (int n = 0; n < 4; ++n)
          y2[(size_t)slot * DIM + (n0 + wc * 64 + n * 16 + lrow)] = acc[m][n][r] * w;
      }
    }
  }
}

// ---------------- combine: out[t] = y2[slot0] + y2[slot1] ------------------
// one block per token, 256 threads x float4 = 1024 floats = DIM
__global__ void combine_kernel(const float* __restrict__ y2, const int* __restrict__ t2s,
                               float* __restrict__ out) {
  int t = blockIdx.x;
  int c = threadIdx.x;
  int s0 = t2s[2 * t], s1 = t2s[2 * t + 1];
  float4 a = *(const float4*)(y2 + (size_t)s0 * DIM + c * 4);
  float4 b = *(const float4*)(y2 + (size_t)s1 * DIM + c * 4);
  float4 o;
  o.x = a.x + b.x; o.y = a.y + b.y; o.z = a.z + b.z; o.w = a.w + b.w;
  *(float4*)(out + (size_t)t * DIM + c * 4) = o;
}

extern "C" void kernel_launch(void* const* d_in, const int* in_sizes, int n_in,
                              void* d_out, int out_size, void* d_ws, size_t ws_size,
                              hipStream_t stream) {
  const float* x  = (const float*)d_in[0];
  const float* gw = (const float*)d_in[1];
  const float* w1 = (const float*)d_in[2];
  const float* w3 = (const float*)d_in[3];
  const float* w2 = (const float*)d_in[4];
  float* out = (float*)d_out;

  // workspace layout (~248 MB); y2 (67MB) aliases w1b+w3b (92MB, dead after gemm1)
  char* base = (char*)d_ws;
  size_t o = 0;
  auto alloc = [&](size_t bytes) {
    void* r = base + o;
    o = (o + bytes + 255) & ~(size_t)255;
    return r;
  };
  u16* xb      = (u16*)alloc((size_t)NTOK * DIM * 2);
  u16* w1b     = (u16*)alloc((size_t)NEXP * HID * DIM * 2);
  u16* w3b     = (u16*)alloc((size_t)NEXP * HID * DIM * 2);
  u16* w2b     = (u16*)alloc((size_t)NEXP * DIM * HID * 2);
  u16* hbuf    = (u16*)alloc((size_t)NPAIR * HID * 2);
  int* pair_tok = (int*)alloc((size_t)NPAIR * 4);
  float* pair_w = (float*)alloc((size_t)NPAIR * 4);
  int* tok_e    = (int*)alloc((size_t)NTOK * 2 * 4);
  float* tok_w  = (float*)alloc((size_t)NTOK * 2 * 4);
  int* t2s      = (int*)alloc((size_t)NTOK * 2 * 4);
  int* cnt      = (int*)alloc(NEXP * 4);
  int* eoff     = (int*)alloc((NEXP + 1) * 4);
  int* fill     = (int*)alloc(NEXP * 4);
  float* y2     = (float*)w1b;   // alias: gemm2 writes after gemm1's last w1b/w3b read

  hipMemsetAsync(cnt, 0, NEXP * sizeof(int), stream);

  cvt_kernel<<<2048, 256, 0, stream>>>(x,  xb,  NTOK * DIM);
  cvt_kernel<<<2048, 256, 0, stream>>>(w1, w1b, NEXP * HID * DIM);
  cvt_kernel<<<2048, 256, 0, stream>>>(w3, w3b, NEXP * HID * DIM);
  cvt_kernel<<<2048, 256, 0, stream>>>(w2, w2b, NEXP * DIM * HID);

  router_kernel<<<NTOK, 64, 0, stream>>>(x, gw, cnt, tok_e, tok_w);
  prefix_kernel<<<1, 64, 0, stream>>>(cnt, eoff, fill);
  scatter_kernel<<<NTOK / 256, 256, 0, stream>>>(tok_e, tok_w, eoff, fill,
                                                 pair_tok, pair_w, t2s);

  gemm1_kernel<<<dim3(NPAIR / G1_BM, HID / G1_BN, NEXP), 256, 0, stream>>>(
      xb, w1b, w3b, hbuf, eoff, pair_tok);
  gemm2_kernel<<<dim3(NPAIR / G2_BM, DIM / G2_BN, NEXP), 256, 0, stream>>>(
      hbuf, w2b, y2, eoff, pair_w);
  combine_kernel<<<NTOK, 256, 0, stream>>>(y2, t2s, out);
}

// Round 4
// 1006.049 us; speedup vs baseline: 1.1389x; 1.0146x over previous
//
#include <hip/hip_runtime.h>
#include <hip/hip_bf16.h>

// Problem constants (from reference)
#define NTOK 8192      // B*T = 4*2048
#define DIM 1024
#define NEXP 8
#define HID 2816
#define NPAIR (NTOK * 2)   // TOP_K = 2

#define BK 64
#define BM 128            // m-tile (shared worklist between gemm1/gemm2)
#define G1_BN 64          // h-columns per block
#define G2_BN 128
#define MAXTILE 144       // >= ceil(NPAIR/BM) + NEXP - 1 = 135

typedef unsigned short u16;
typedef __attribute__((ext_vector_type(8))) short short8;   // 8 x bf16 fragment
typedef __attribute__((ext_vector_type(4))) float f32x4;    // MFMA accumulator

static __device__ __forceinline__ u16 f2bf(float f) {
  union { float f; unsigned u; } v; v.f = f;
  unsigned r = v.u + 0x7fff + ((v.u >> 16) & 1);  // RTNE
  return (u16)(r >> 16);
}

// async global->LDS, 16B per lane; LDS dest is wave-uniform base + lane*16B
static __device__ __forceinline__ void gload16(const void* g, void* l) {
  __builtin_amdgcn_global_load_lds(
      (const __attribute__((address_space(1))) unsigned*)(g),
      (__attribute__((address_space(3))) unsigned*)(l), 16, 0, 0);
}

// ---------------- fp32 -> bf16 conversion (vectorized, grid-stride) ----------
__global__ void cvt_kernel(const float* __restrict__ src, u16* __restrict__ dst, int n) {
  int stride = gridDim.x * blockDim.x;
  for (int i = blockIdx.x * blockDim.x + threadIdx.x; i * 4 < n; i += stride) {
    float4 v = *reinterpret_cast<const float4*>(src + (size_t)i * 4);
    ushort4 o;
    o.x = f2bf(v.x); o.y = f2bf(v.y); o.z = f2bf(v.z); o.w = f2bf(v.w);
    *reinterpret_cast<ushort4*>(dst + (size_t)i * 4) = o;
  }
}

// ---------------- router: logits -> softmax -> top2 -> renorm ----------------
__global__ void router_kernel(const float* __restrict__ x, const float* __restrict__ gw,
                              int* __restrict__ cnt, int* __restrict__ tok_e,
                              float* __restrict__ tok_w) {
  int t = blockIdx.x;
  int lane = threadIdx.x;  // 64 threads = 1 wave
  const float* xr = x + (size_t)t * DIM;
  float acc[NEXP];
#pragma unroll
  for (int e = 0; e < NEXP; ++e) acc[e] = 0.f;
  for (int d = lane; d < DIM; d += 64) {
    float xv = xr[d];
#pragma unroll
    for (int e = 0; e < NEXP; ++e) acc[e] += xv * gw[e * DIM + d];
  }
#pragma unroll
  for (int e = 0; e < NEXP; ++e) {
#pragma unroll
    for (int o = 32; o > 0; o >>= 1) acc[e] += __shfl_xor(acc[e], o);
  }
  if (lane == 0) {
    float m = acc[0];
#pragma unroll
    for (int e = 1; e < NEXP; ++e) m = fmaxf(m, acc[e]);
    float p[NEXP];
#pragma unroll
    for (int e = 0; e < NEXP; ++e) p[e] = __expf(acc[e] - m);
    int e0 = 0; float b0 = p[0];
#pragma unroll
    for (int e = 1; e < NEXP; ++e) if (p[e] > b0) { e0 = e; b0 = p[e]; }
    int e1 = -1; float b1 = -1.f;
#pragma unroll
    for (int e = 0; e < NEXP; ++e) if (e != e0 && p[e] > b1) { e1 = e; b1 = p[e]; }
    float inv = 1.f / (b0 + b1);   // softmax denom cancels in the renorm ratio
    atomicAdd(&cnt[e0], 1);
    atomicAdd(&cnt[e1], 1);
    tok_e[2 * t] = e0; tok_e[2 * t + 1] = e1;
    tok_w[2 * t] = b0 * inv; tok_w[2 * t + 1] = b1 * inv;
  }
}

// ------- prefix over experts + flat m-tile worklist (<=135 tiles) ----------
__global__ void prefix_kernel(const int* __restrict__ cnt, int* __restrict__ off,
                              int* __restrict__ fill, int* __restrict__ tile_e,
                              int* __restrict__ tile_mb, int* __restrict__ ntiles) {
  if (threadIdx.x == 0 && blockIdx.x == 0) {
    int s = 0, nt = 0;
    for (int e = 0; e < NEXP; ++e) {
      off[e] = s;
      for (int mb = 0; mb < cnt[e]; mb += BM) {
        tile_e[nt] = e; tile_mb[nt] = s + mb; ++nt;
      }
      s += cnt[e]; fill[e] = 0;
    }
    off[NEXP] = s;
    *ntiles = nt;
  }
}

// ---------------- scatter tokens into per-expert slot lists ----------------
__global__ void scatter_kernel(const int* __restrict__ tok_e, const float* __restrict__ tok_w,
                               const int* __restrict__ off, int* __restrict__ fill,
                               int* __restrict__ pair_tok, float* __restrict__ pair_w,
                               int* __restrict__ t2s) {
  int t = blockIdx.x * blockDim.x + threadIdx.x;
  if (t >= NTOK) return;
#pragma unroll
  for (int k = 0; k < 2; ++k) {
    int e = tok_e[2 * t + k];
    int slot = off[e] + atomicAdd(&fill[e], 1);
    pair_tok[slot] = t;
    pair_w[slot] = tok_w[2 * t + k];
    t2s[2 * t + k] = slot;
  }
}

// ---------------- GEMM1: h = silu(x @ w1^T) * (x @ w3^T) -------------------
// 128x64 tile, 4 waves (2x2), wave = 64x32 per matmul. Double-buffered LDS
// (64KB), ONE barrier per K-step, stage issued before compute (T3-minimum).
__launch_bounds__(256, 2)
__global__ void gemm1_kernel(const u16* __restrict__ xb, const u16* __restrict__ w1b,
                             const u16* __restrict__ w3b, u16* __restrict__ hbuf,
                             const int* __restrict__ off, const int* __restrict__ pair_tok,
                             const int* __restrict__ tile_e, const int* __restrict__ tile_mb,
                             const int* __restrict__ ntiles) {
  int ti = blockIdx.x;
  if (ti >= *ntiles) return;
  int e = tile_e[ti];
  int mbase = tile_mb[ti];
  int nrows = off[e + 1] - mbase; if (nrows > BM) nrows = BM;
  int n0 = blockIdx.y * G1_BN;

  __shared__ u16 As[2][BM * BK];      // 2 x 16KB
  __shared__ u16 B1s[2][G1_BN * BK];  // 2 x 8KB
  __shared__ u16 B3s[2][G1_BN * BK];  // 2 x 8KB

  int tid = threadIdx.x;
  int lane = tid & 63;
  int wid = tid >> 6;
  int wr = wid >> 1, wc = wid & 1;          // 2(M) x 2(N) wave grid
  int lrow = lane & 15, kgrp = lane >> 4;

  // staging: issue i covers rows i*32 + tid/8, col (tid%8)*8 (8 u16 = 16B)
  int srow = tid >> 3;          // 0..31
  int scol = (tid & 7) * 8;
  const u16* pA[4]; const u16* pB1[2]; const u16* pB3[2];
  const u16* w1base = w1b + (size_t)e * HID * DIM;
  const u16* w3base = w3b + (size_t)e * HID * DIM;
#pragma unroll
  for (int i = 0; i < 4; ++i) {
    int r = i * 32 + srow;
    int ra = r < nrows ? r : nrows - 1;       // clamp ragged tile
    int tok = pair_tok[mbase + ra];
    pA[i] = xb + (size_t)tok * DIM + scol;
  }
#pragma unroll
  for (int i = 0; i < 2; ++i) {
    int r = i * 32 + srow;
    pB1[i] = w1base + (size_t)(n0 + r) * DIM + scol;
    pB3[i] = w3base + (size_t)(n0 + r) * DIM + scol;
  }

  f32x4 acc1[4][2], acc3[4][2];
#pragma unroll
  for (int m = 0; m < 4; ++m)
#pragma unroll
    for (int n = 0; n < 2; ++n) { acc1[m][n] = (f32x4)0.f; acc3[m][n] = (f32x4)0.f; }

  auto stage = [&](int b, int kk) {
#pragma unroll
    for (int i = 0; i < 4; ++i)
      gload16(pA[i] + kk, &As[b][i * 2048 + wid * 512]);
#pragma unroll
    for (int i = 0; i < 2; ++i) {
      gload16(pB1[i] + kk, &B1s[b][i * 2048 + wid * 512]);
      gload16(pB3[i] + kk, &B3s[b][i * 2048 + wid * 512]);
    }
  };
  auto compute = [&](int b) {
#pragma unroll
    for (int ks = 0; ks < 2; ++ks) {
      int kc = ks * 32 + kgrp * 8;
      short8 a[4], b1[2], b3[2];
#pragma unroll
      for (int m = 0; m < 4; ++m)
        a[m] = *(const short8*)&As[b][(wr * 64 + m * 16 + lrow) * BK + kc];
#pragma unroll
      for (int n = 0; n < 2; ++n) {
        b1[n] = *(const short8*)&B1s[b][(wc * 32 + n * 16 + lrow) * BK + kc];
        b3[n] = *(const short8*)&B3s[b][(wc * 32 + n * 16 + lrow) * BK + kc];
      }
#pragma unroll
      for (int m = 0; m < 4; ++m)
#pragma unroll
        for (int n = 0; n < 2; ++n) {
          acc1[m][n] = __builtin_amdgcn_mfma_f32_16x16x32_bf16(a[m], b1[n], acc1[m][n], 0, 0, 0);
          acc3[m][n] = __builtin_amdgcn_mfma_f32_16x16x32_bf16(a[m], b3[n], acc3[m][n], 0, 0, 0);
        }
    }
  };

  int cur = 0;
  stage(0, 0);
  __syncthreads();                       // vmcnt drained: tile 0 ready
  for (int kk = BK; kk < DIM; kk += BK) {
    stage(cur ^ 1, kk);                  // loads fly under the MFMAs below
    compute(cur);
    __syncthreads();                     // next tile ready + readers done
    cur ^= 1;
  }
  compute(cur);

  // epilogue: silu(acc1)*acc3 -> bf16 h
#pragma unroll
  for (int m = 0; m < 4; ++m)
#pragma unroll
    for (int n = 0; n < 2; ++n)
#pragma unroll
      for (int r = 0; r < 4; ++r) {
        int rowt = wr * 64 + m * 16 + kgrp * 4 + r;   // C/D: row=(lane>>4)*4+r, col=lane&15
        if (rowt < nrows) {
          float v1 = acc1[m][n][r], v3 = acc3[m][n][r];
          float hv = v1 / (1.f + __expf(-v1)) * v3;
          hbuf[(size_t)(mbase + rowt) * HID + (n0 + wc * 32 + n * 16 + lrow)] = f2bf(hv);
        }
      }
}

// ---------------- GEMM2: y2[slot] = (h @ w2^T) * pair_w --------------------
// 128x128 tile, 4 waves each 64x64. Same dbuf single-barrier K-loop.
__launch_bounds__(256, 2)
__global__ void gemm2_kernel(const u16* __restrict__ hbuf, const u16* __restrict__ w2b,
                             float* __restrict__ y2, const int* __restrict__ off,
                             const float* __restrict__ pair_w,
                             const int* __restrict__ tile_e, const int* __restrict__ tile_mb,
                             const int* __restrict__ ntiles) {
  int ti = blockIdx.x;
  if (ti >= *ntiles) return;
  int e = tile_e[ti];
  int mbase = tile_mb[ti];
  int nrows = off[e + 1] - mbase; if (nrows > BM) nrows = BM;
  int n0 = blockIdx.y * G2_BN;

  __shared__ u16 As[2][BM * BK];      // 2 x 16KB
  __shared__ u16 Bs[2][G2_BN * BK];   // 2 x 16KB

  int tid = threadIdx.x;
  int lane = tid & 63;
  int wid = tid >> 6;
  int wr = wid >> 1, wc = wid & 1;
  int lrow = lane & 15, kgrp = lane >> 4;

  int srow = tid >> 3;
  int scol = (tid & 7) * 8;
  const u16* pA[4]; const u16* pB[4];
  const u16* w2base = w2b + (size_t)e * DIM * HID;
#pragma unroll
  for (int i = 0; i < 4; ++i) {
    int r = i * 32 + srow;
    int ra = r < nrows ? r : nrows - 1;
    pA[i] = hbuf + (size_t)(mbase + ra) * HID + scol;
    pB[i] = w2base + (size_t)(n0 + r) * HID + scol;
  }

  f32x4 acc[4][4];
#pragma unroll
  for (int m = 0; m < 4; ++m)
#pragma unroll
    for (int n = 0; n < 4; ++n) acc[m][n] = (f32x4)0.f;

  auto stage = [&](int b, int kk) {
#pragma unroll
    for (int i = 0; i < 4; ++i) {
      gload16(pA[i] + kk, &As[b][i * 2048 + wid * 512]);
      gload16(pB[i] + kk, &Bs[b][i * 2048 + wid * 512]);
    }
  };
  auto compute = [&](int b) {
#pragma unroll
    for (int ks = 0; ks < 2; ++ks) {
      int kc = ks * 32 + kgrp * 8;
      short8 a[4], bb[4];
#pragma unroll
      for (int m = 0; m < 4; ++m)
        a[m] = *(const short8*)&As[b][(wr * 64 + m * 16 + lrow) * BK + kc];
#pragma unroll
      for (int n = 0; n < 4; ++n)
        bb[n] = *(const short8*)&Bs[b][(wc * 64 + n * 16 + lrow) * BK + kc];
#pragma unroll
      for (int m = 0; m < 4; ++m)
#pragma unroll
        for (int n = 0; n < 4; ++n)
          acc[m][n] = __builtin_amdgcn_mfma_f32_16x16x32_bf16(a[m], bb[n], acc[m][n], 0, 0, 0);
    }
  };

  int cur = 0;
  stage(0, 0);
  __syncthreads();
  for (int kk = BK; kk < HID; kk += BK) {
    stage(cur ^ 1, kk);
    compute(cur);
    __syncthreads();
    cur ^= 1;
  }
  compute(cur);

#pragma unroll
  for (int m = 0; m < 4; ++m) {
#pragma unroll
    for (int r = 0; r < 4; ++r) {
      int rowt = wr * 64 + m * 16 + kgrp * 4 + r;
      if (rowt < nrows) {
        int slot = mbase + rowt;
        float w = pair_w[slot];
#pragma unroll
        for (int n = 0; n < 4; ++n)
          y2[(size_t)slot * DIM + (n0 + wc * 64 + n * 16 + lrow)] = acc[m][n][r] * w;
      }
    }
  }
}

// ---------------- combine: out[t] = y2[slot0] + y2[slot1] ------------------
__global__ void combine_kernel(const float* __restrict__ y2, const int* __restrict__ t2s,
                               float* __restrict__ out) {
  int t = blockIdx.x;
  int c = threadIdx.x;
  int s0 = t2s[2 * t], s1 = t2s[2 * t + 1];
  float4 a = *(const float4*)(y2 + (size_t)s0 * DIM + c * 4);
  float4 b = *(const float4*)(y2 + (size_t)s1 * DIM + c * 4);
  float4 o;
  o.x = a.x + b.x; o.y = a.y + b.y; o.z = a.z + b.z; o.w = a.w + b.w;
  *(float4*)(out + (size_t)t * DIM + c * 4) = o;
}

extern "C" void kernel_launch(void* const* d_in, const int* in_sizes, int n_in,
                              void* d_out, int out_size, void* d_ws, size_t ws_size,
                              hipStream_t stream) {
  const float* x  = (const float*)d_in[0];
  const float* gw = (const float*)d_in[1];
  const float* w1 = (const float*)d_in[2];
  const float* w3 = (const float*)d_in[3];
  const float* w2 = (const float*)d_in[4];
  float* out = (float*)d_out;

  // workspace layout (~248 MB); y2 (67MB) aliases w1b+w3b (92MB, dead after gemm1)
  char* base = (char*)d_ws;
  size_t o = 0;
  auto alloc = [&](size_t bytes) {
    void* r = base + o;
    o = (o + bytes + 255) & ~(size_t)255;
    return r;
  };
  u16* xb      = (u16*)alloc((size_t)NTOK * DIM * 2);
  u16* w1b     = (u16*)alloc((size_t)NEXP * HID * DIM * 2);
  u16* w3b     = (u16*)alloc((size_t)NEXP * HID * DIM * 2);
  u16* w2b     = (u16*)alloc((size_t)NEXP * DIM * HID * 2);
  u16* hbuf    = (u16*)alloc((size_t)NPAIR * HID * 2);
  int* pair_tok = (int*)alloc((size_t)NPAIR * 4);
  float* pair_w = (float*)alloc((size_t)NPAIR * 4);
  int* tok_e    = (int*)alloc((size_t)NTOK * 2 * 4);
  float* tok_w  = (float*)alloc((size_t)NTOK * 2 * 4);
  int* t2s      = (int*)alloc((size_t)NTOK * 2 * 4);
  int* cnt      = (int*)alloc(NEXP * 4);
  int* eoff     = (int*)alloc((NEXP + 1) * 4);
  int* fill     = (int*)alloc(NEXP * 4);
  int* tile_e   = (int*)alloc(MAXTILE * 4);
  int* tile_mb  = (int*)alloc(MAXTILE * 4);
  int* ntiles   = (int*)alloc(4);
  float* y2     = (float*)w1b;   // alias: gemm2 writes after gemm1's last w1b/w3b read

  hipMemsetAsync(cnt, 0, NEXP * sizeof(int), stream);

  cvt_kernel<<<2048, 256, 0, stream>>>(x,  xb,  NTOK * DIM);
  cvt_kernel<<<2048, 256, 0, stream>>>(w1, w1b, NEXP * HID * DIM);
  cvt_kernel<<<2048, 256, 0, stream>>>(w3, w3b, NEXP * HID * DIM);
  cvt_kernel<<<2048, 256, 0, stream>>>(w2, w2b, NEXP * DIM * HID);

  router_kernel<<<NTOK, 64, 0, stream>>>(x, gw, cnt, tok_e, tok_w);
  prefix_kernel<<<1, 64, 0, stream>>>(cnt, eoff, fill, tile_e, tile_mb, ntiles);
  scatter_kernel<<<NTOK / 256, 256, 0, stream>>>(tok_e, tok_w, eoff, fill,
                                                 pair_tok, pair_w, t2s);

  gemm1_kernel<<<dim3(MAXTILE, HID / G1_BN, 1), 256, 0, stream>>>(
      xb, w1b, w3b, hbuf, eoff, pair_tok, tile_e, tile_mb, ntiles);
  gemm2_kernel<<<dim3(MAXTILE, DIM / G2_BN, 1), 256, 0, stream>>>(
      hbuf, w2b, y2, eoff, pair_w, tile_e, tile_mb, ntiles);
  combine_kernel<<<NTOK, 256, 0, stream>>>(y2, t2s, out);
}

// Round 5
// 946.980 us; speedup vs baseline: 1.2100x; 1.0624x over previous
//
#include <hip/hip_runtime.h>
#include <hip/hip_bf16.h>

// Problem constants (from reference)
#define NTOK 8192      // B*T = 4*2048
#define DIM 1024
#define NEXP 8
#define HID 2816
#define NPAIR (NTOK * 2)   // TOP_K = 2

#define BK 64
#define BM 256            // m-tile (shared worklist between gemm1/gemm2)
#define G1_BN 128         // h-columns per block (fused: 128 w1-rows + 128 w3-rows)
#define G2_BN 256
#define MAXTILE 72        // >= ceil(NPAIR/BM) + NEXP - 1 = 71
#define G1_NSL (HID / G1_BN)   // 22
#define G2_NSL (DIM / G2_BN)   // 4
#define G1_NWG (MAXTILE * G1_NSL)  // 1584 (div by 8)
#define G2_NWG (MAXTILE * G2_NSL)  // 288  (div by 8)

typedef unsigned short u16;
typedef __attribute__((ext_vector_type(8))) short short8;   // 8 x bf16 fragment
typedef __attribute__((ext_vector_type(4))) float f32x4;    // MFMA accumulator

static __device__ __forceinline__ u16 f2bf(float f) {
  union { float f; unsigned u; } v; v.f = f;
  unsigned r = v.u + 0x7fff + ((v.u >> 16) & 1);  // RTNE
  return (u16)(r >> 16);
}

// async global->LDS, 16B per lane; LDS dest is wave-uniform base + lane*16B
static __device__ __forceinline__ void gload16(const void* g, void* l) {
  __builtin_amdgcn_global_load_lds(
      (const __attribute__((address_space(1))) unsigned*)(g),
      (__attribute__((address_space(3))) unsigned*)(l), 16, 0, 0);
}

// ---------------- fp32 -> bf16 conversion (vectorized, grid-stride) ----------
__global__ void cvt_kernel(const float* __restrict__ src, u16* __restrict__ dst, int n) {
  int stride = gridDim.x * blockDim.x;
  for (int i = blockIdx.x * blockDim.x + threadIdx.x; i * 4 < n; i += stride) {
    float4 v = *reinterpret_cast<const float4*>(src + (size_t)i * 4);
    ushort4 o;
    o.x = f2bf(v.x); o.y = f2bf(v.y); o.z = f2bf(v.z); o.w = f2bf(v.w);
    *reinterpret_cast<ushort4*>(dst + (size_t)i * 4) = o;
  }
}

// ---------------- router: logits -> softmax -> top2 -> renorm ----------------
__global__ void router_kernel(const float* __restrict__ x, const float* __restrict__ gw,
                              int* __restrict__ cnt, int* __restrict__ tok_e,
                              float* __restrict__ tok_w) {
  int t = blockIdx.x;
  int lane = threadIdx.x;  // 64 threads = 1 wave
  const float* xr = x + (size_t)t * DIM;
  float acc[NEXP];
#pragma unroll
  for (int e = 0; e < NEXP; ++e) acc[e] = 0.f;
  for (int d = lane; d < DIM; d += 64) {
    float xv = xr[d];
#pragma unroll
    for (int e = 0; e < NEXP; ++e) acc[e] += xv * gw[e * DIM + d];
  }
#pragma unroll
  for (int e = 0; e < NEXP; ++e) {
#pragma unroll
    for (int o = 32; o > 0; o >>= 1) acc[e] += __shfl_xor(acc[e], o);
  }
  if (lane == 0) {
    float m = acc[0];
#pragma unroll
    for (int e = 1; e < NEXP; ++e) m = fmaxf(m, acc[e]);
    float p[NEXP];
#pragma unroll
    for (int e = 0; e < NEXP; ++e) p[e] = __expf(acc[e] - m);
    int e0 = 0; float b0 = p[0];
#pragma unroll
    for (int e = 1; e < NEXP; ++e) if (p[e] > b0) { e0 = e; b0 = p[e]; }
    int e1 = -1; float b1 = -1.f;
#pragma unroll
    for (int e = 0; e < NEXP; ++e) if (e != e0 && p[e] > b1) { e1 = e; b1 = p[e]; }
    float inv = 1.f / (b0 + b1);   // softmax denom cancels in the renorm ratio
    atomicAdd(&cnt[e0], 1);
    atomicAdd(&cnt[e1], 1);
    tok_e[2 * t] = e0; tok_e[2 * t + 1] = e1;
    tok_w[2 * t] = b0 * inv; tok_w[2 * t + 1] = b1 * inv;
  }
}

// ------- prefix over experts + flat m-tile worklist (<=71 tiles @BM=256) ----
__global__ void prefix_kernel(const int* __restrict__ cnt, int* __restrict__ off,
                              int* __restrict__ fill, int* __restrict__ tile_e,
                              int* __restrict__ tile_mb, int* __restrict__ ntiles) {
  if (threadIdx.x == 0 && blockIdx.x == 0) {
    int s = 0, nt = 0;
    for (int e = 0; e < NEXP; ++e) {
      off[e] = s;
      for (int mb = 0; mb < cnt[e]; mb += BM) {
        tile_e[nt] = e; tile_mb[nt] = s + mb; ++nt;
      }
      s += cnt[e]; fill[e] = 0;
    }
    off[NEXP] = s;
    *ntiles = nt;
  }
}

// ---------------- scatter tokens into per-expert slot lists ----------------
__global__ void scatter_kernel(const int* __restrict__ tok_e, const float* __restrict__ tok_w,
                               const int* __restrict__ off, int* __restrict__ fill,
                               int* __restrict__ pair_tok, float* __restrict__ pair_w,
                               int* __restrict__ t2s) {
  int t = blockIdx.x * blockDim.x + threadIdx.x;
  if (t >= NTOK) return;
#pragma unroll
  for (int k = 0; k < 2; ++k) {
    int e = tok_e[2 * t + k];
    int slot = off[e] + atomicAdd(&fill[e], 1);
    pair_tok[slot] = t;
    pair_w[slot] = tok_w[2 * t + k];
    t2s[2 * t + k] = slot;
  }
}

// ---------------- GEMM1: h = silu(x @ w1^T) * (x @ w3^T) -------------------
// 256x128 tile (fused w1+w3), 8 waves (2Mx4N), wave = 128x32 per matmul.
// LDS 128KB dbuf, one barrier per K-step, T1 XCD swizzle on flat 1D grid.
__launch_bounds__(512, 2)
__global__ void gemm1_kernel(const u16* __restrict__ xb, const u16* __restrict__ w1b,
                             const u16* __restrict__ w3b, u16* __restrict__ hbuf,
                             const int* __restrict__ off, const int* __restrict__ pair_tok,
                             const int* __restrict__ tile_e, const int* __restrict__ tile_mb,
                             const int* __restrict__ ntiles) {
  // bijective XCD swizzle (G1_NWG % 8 == 0): chunk of 198 consecutive per XCD
  int bid = blockIdx.x;
  int swz = (bid & 7) * (G1_NWG / 8) + (bid >> 3);
  int ti = swz / G1_NSL;        // A-major: consecutive same-XCD blocks share A-tile
  int n0 = (swz % G1_NSL) * G1_BN;
  if (ti >= *ntiles) return;
  int e = tile_e[ti];
  int mbase = tile_mb[ti];
  int nrows = off[e + 1] - mbase; if (nrows > BM) nrows = BM;

  __shared__ u16 As[2][BM * BK];       // 2 x 32KB
  __shared__ u16 B1s[2][G1_BN * BK];   // 2 x 16KB
  __shared__ u16 B3s[2][G1_BN * BK];   // 2 x 16KB

  int tid = threadIdx.x;
  int lane = tid & 63;
  int wid = tid >> 6;                  // 0..7
  int wr = wid >> 2, wc = wid & 3;     // 2(M) x 4(N) wave grid; wave: 128 x 32
  int lrow = lane & 15, kgrp = lane >> 4;

  // staging: instr i covers rows i*64 + tid/8, col (tid%8)*8 (8 u16 = 16B)
  int srow = tid >> 3;          // 0..63
  int scol = (tid & 7) * 8;
  const u16* pA[4]; const u16* pB1[2]; const u16* pB3[2];
  const u16* w1base = w1b + (size_t)e * HID * DIM;
  const u16* w3base = w3b + (size_t)e * HID * DIM;
#pragma unroll
  for (int i = 0; i < 4; ++i) {
    int r = i * 64 + srow;
    int ra = r < nrows ? r : nrows - 1;       // clamp ragged tile
    int tok = pair_tok[mbase + ra];
    pA[i] = xb + (size_t)tok * DIM + scol;
  }
#pragma unroll
  for (int i = 0; i < 2; ++i) {
    int r = i * 64 + srow;
    pB1[i] = w1base + (size_t)(n0 + r) * DIM + scol;
    pB3[i] = w3base + (size_t)(n0 + r) * DIM + scol;
  }

  f32x4 acc1[8][2], acc3[8][2];
#pragma unroll
  for (int m = 0; m < 8; ++m)
#pragma unroll
    for (int n = 0; n < 2; ++n) { acc1[m][n] = (f32x4)0.f; acc3[m][n] = (f32x4)0.f; }

  auto stage = [&](int b, int kk) {
#pragma unroll
    for (int i = 0; i < 4; ++i)
      gload16(pA[i] + kk, &As[b][(i * 64 + wid * 8) * BK]);
#pragma unroll
    for (int i = 0; i < 2; ++i) {
      gload16(pB1[i] + kk, &B1s[b][(i * 64 + wid * 8) * BK]);
      gload16(pB3[i] + kk, &B3s[b][(i * 64 + wid * 8) * BK]);
    }
  };
  auto compute = [&](int b) {
#pragma unroll
    for (int ks = 0; ks < 2; ++ks) {
      int kc = ks * 32 + kgrp * 8;
      short8 a[8], b1[2], b3[2];
#pragma unroll
      for (int m = 0; m < 8; ++m)
        a[m] = *(const short8*)&As[b][(wr * 128 + m * 16 + lrow) * BK + kc];
#pragma unroll
      for (int n = 0; n < 2; ++n) {
        b1[n] = *(const short8*)&B1s[b][(wc * 32 + n * 16 + lrow) * BK + kc];
        b3[n] = *(const short8*)&B3s[b][(wc * 32 + n * 16 + lrow) * BK + kc];
      }
#pragma unroll
      for (int m = 0; m < 8; ++m)
#pragma unroll
        for (int n = 0; n < 2; ++n) {
          acc1[m][n] = __builtin_amdgcn_mfma_f32_16x16x32_bf16(a[m], b1[n], acc1[m][n], 0, 0, 0);
          acc3[m][n] = __builtin_amdgcn_mfma_f32_16x16x32_bf16(a[m], b3[n], acc3[m][n], 0, 0, 0);
        }
    }
  };

  int cur = 0;
  stage(0, 0);
  __syncthreads();                       // vmcnt drained: tile 0 ready
  for (int kk = BK; kk < DIM; kk += BK) {
    stage(cur ^ 1, kk);                  // loads fly under the MFMAs below
    compute(cur);
    __syncthreads();                     // next tile ready + readers done
    cur ^= 1;
  }
  compute(cur);

  // epilogue: silu(acc1)*acc3 -> bf16 h
#pragma unroll
  for (int m = 0; m < 8; ++m)
#pragma unroll
    for (int n = 0; n < 2; ++n)
#pragma unroll
      for (int r = 0; r < 4; ++r) {
        int rowt = wr * 128 + m * 16 + kgrp * 4 + r;   // C/D: row=(lane>>4)*4+r, col=lane&15
        if (rowt < nrows) {
          float v1 = acc1[m][n][r], v3 = acc3[m][n][r];
          float hv = v1 / (1.f + __expf(-v1)) * v3;
          hbuf[(size_t)(mbase + rowt) * HID + (n0 + wc * 32 + n * 16 + lrow)] = f2bf(hv);
        }
      }
}

// ---------------- GEMM2: y2[slot] = (h @ w2^T) * pair_w --------------------
// 256x256 tile, 8 waves (2Mx4N), wave = 128x64. Same dbuf single-barrier loop.
__launch_bounds__(512, 2)
__global__ void gemm2_kernel(const u16* __restrict__ hbuf, const u16* __restrict__ w2b,
                             float* __restrict__ y2, const int* __restrict__ off,
                             const float* __restrict__ pair_w,
                             const int* __restrict__ tile_e, const int* __restrict__ tile_mb,
                             const int* __restrict__ ntiles) {
  int bid = blockIdx.x;
  int swz = (bid & 7) * (G2_NWG / 8) + (bid >> 3);
  int ti = swz / G2_NSL;
  int n0 = (swz % G2_NSL) * G2_BN;
  if (ti >= *ntiles) return;
  int e = tile_e[ti];
  int mbase = tile_mb[ti];
  int nrows = off[e + 1] - mbase; if (nrows > BM) nrows = BM;

  __shared__ u16 As[2][BM * BK];      // 2 x 32KB
  __shared__ u16 Bs[2][G2_BN * BK];   // 2 x 32KB

  int tid = threadIdx.x;
  int lane = tid & 63;
  int wid = tid >> 6;
  int wr = wid >> 2, wc = wid & 3;    // wave: 128 x 64
  int lrow = lane & 15, kgrp = lane >> 4;

  int srow = tid >> 3;
  int scol = (tid & 7) * 8;
  const u16* pA[4]; const u16* pB[4];
  const u16* w2base = w2b + (size_t)e * DIM * HID;
#pragma unroll
  for (int i = 0; i < 4; ++i) {
    int r = i * 64 + srow;
    int ra = r < nrows ? r : nrows - 1;
    pA[i] = hbuf + (size_t)(mbase + ra) * HID + scol;
    pB[i] = w2base + (size_t)(n0 + r) * HID + scol;
  }

  f32x4 acc[8][4];
#pragma unroll
  for (int m = 0; m < 8; ++m)
#pragma unroll
    for (int n = 0; n < 4; ++n) acc[m][n] = (f32x4)0.f;

  auto stage = [&](int b, int kk) {
#pragma unroll
    for (int i = 0; i < 4; ++i) {
      gload16(pA[i] + kk, &As[b][(i * 64 + wid * 8) * BK]);
      gload16(pB[i] + kk, &Bs[b][(i * 64 + wid * 8) * BK]);
    }
  };
  auto compute = [&](int b) {
#pragma unroll
    for (int ks = 0; ks < 2; ++ks) {
      int kc = ks * 32 + kgrp * 8;
      short8 a[8], bb[4];
#pragma unroll
      for (int m = 0; m < 8; ++m)
        a[m] = *(const short8*)&As[b][(wr * 128 + m * 16 + lrow) * BK + kc];
#pragma unroll
      for (int n = 0; n < 4; ++n)
        bb[n] = *(const short8*)&Bs[b][(wc * 64 + n * 16 + lrow) * BK + kc];
#pragma unroll
      for (int m = 0; m < 8; ++m)
#pragma unroll
        for (int n = 0; n < 4; ++n)
          acc[m][n] = __builtin_amdgcn_mfma_f32_16x16x32_bf16(a[m], bb[n], acc[m][n], 0, 0, 0);
    }
  };

  int cur = 0;
  stage(0, 0);
  __syncthreads();
  for (int kk = BK; kk < HID; kk += BK) {
    stage(cur ^ 1, kk);
    compute(cur);
    __syncthreads();
    cur ^= 1;
  }
  compute(cur);

#pragma unroll
  for (int m = 0; m < 8; ++m) {
#pragma unroll
    for (int r = 0; r < 4; ++r) {
      int rowt = wr * 128 + m * 16 + kgrp * 4 + r;
      if (rowt < nrows) {
        int slot = mbase + rowt;
        float w = pair_w[slot];
#pragma unroll
        for (int n = 0; n < 4; ++n)
          y2[(size_t)slot * DIM + (n0 + wc * 64 + n * 16 + lrow)] = acc[m][n][r] * w;
      }
    }
  }
}

// ---------------- combine: out[t] = y2[slot0] + y2[slot1] ------------------
__global__ void combine_kernel(const float* __restrict__ y2, const int* __restrict__ t2s,
                               float* __restrict__ out) {
  int t = blockIdx.x;
  int c = threadIdx.x;
  int s0 = t2s[2 * t], s1 = t2s[2 * t + 1];
  float4 a = *(const float4*)(y2 + (size_t)s0 * DIM + c * 4);
  float4 b = *(const float4*)(y2 + (size_t)s1 * DIM + c * 4);
  float4 o;
  o.x = a.x + b.x; o.y = a.y + b.y; o.z = a.z + b.z; o.w = a.w + b.w;
  *(float4*)(out + (size_t)t * DIM + c * 4) = o;
}

extern "C" void kernel_launch(void* const* d_in, const int* in_sizes, int n_in,
                              void* d_out, int out_size, void* d_ws, size_t ws_size,
                              hipStream_t stream) {
  const float* x  = (const float*)d_in[0];
  const float* gw = (const float*)d_in[1];
  const float* w1 = (const float*)d_in[2];
  const float* w3 = (const float*)d_in[3];
  const float* w2 = (const float*)d_in[4];
  float* out = (float*)d_out;

  // workspace layout (~248 MB); y2 (67MB) aliases w1b+w3b (92MB, dead after gemm1)
  char* base = (char*)d_ws;
  size_t o = 0;
  auto alloc = [&](size_t bytes) {
    void* r = base + o;
    o = (o + bytes + 255) & ~(size_t)255;
    return r;
  };
  u16* xb      = (u16*)alloc((size_t)NTOK * DIM * 2);
  u16* w1b     = (u16*)alloc((size_t)NEXP * HID * DIM * 2);
  u16* w3b     = (u16*)alloc((size_t)NEXP * HID * DIM * 2);
  u16* w2b     = (u16*)alloc((size_t)NEXP * DIM * HID * 2);
  u16* hbuf    = (u16*)alloc((size_t)NPAIR * HID * 2);
  int* pair_tok = (int*)alloc((size_t)NPAIR * 4);
  float* pair_w = (float*)alloc((size_t)NPAIR * 4);
  int* tok_e    = (int*)alloc((size_t)NTOK * 2 * 4);
  float* tok_w  = (float*)alloc((size_t)NTOK * 2 * 4);
  int* t2s      = (int*)alloc((size_t)NTOK * 2 * 4);
  int* cnt      = (int*)alloc(NEXP * 4);
  int* eoff     = (int*)alloc((NEXP + 1) * 4);
  int* fill     = (int*)alloc(NEXP * 4);
  int* tile_e   = (int*)alloc(MAXTILE * 4);
  int* tile_mb  = (int*)alloc(MAXTILE * 4);
  int* ntiles   = (int*)alloc(4);
  float* y2     = (float*)w1b;   // alias: gemm2 writes after gemm1's last w1b/w3b read

  hipMemsetAsync(cnt, 0, NEXP * sizeof(int), stream);

  cvt_kernel<<<2048, 256, 0, stream>>>(x,  xb,  NTOK * DIM);
  cvt_kernel<<<2048, 256, 0, stream>>>(w1, w1b, NEXP * HID * DIM);
  cvt_kernel<<<2048, 256, 0, stream>>>(w3, w3b, NEXP * HID * DIM);
  cvt_kernel<<<2048, 256, 0, stream>>>(w2, w2b, NEXP * DIM * HID);

  router_kernel<<<NTOK, 64, 0, stream>>>(x, gw, cnt, tok_e, tok_w);
  prefix_kernel<<<1, 64, 0, stream>>>(cnt, eoff, fill, tile_e, tile_mb, ntiles);
  scatter_kernel<<<NTOK / 256, 256, 0, stream>>>(tok_e, tok_w, eoff, fill,
                                                 pair_tok, pair_w, t2s);

  gemm1_kernel<<<G1_NWG, 512, 0, stream>>>(
      xb, w1b, w3b, hbuf, eoff, pair_tok, tile_e, tile_mb, ntiles);
  gemm2_kernel<<<G2_NWG, 512, 0, stream>>>(
      hbuf, w2b, y2, eoff, pair_w, tile_e, tile_mb, ntiles);
  combine_kernel<<<NTOK, 256, 0, stream>>>(y2, t2s, out);
}